// Round 4
// baseline (160.065 us; speedup 1.0000x reference)
//
#include <hip/hip_runtime.h>
#include <hip/hip_bf16.h>
#include <stdint.h>

// ---------- types ----------
typedef __bf16 bf16x8 __attribute__((ext_vector_type(8)));
typedef float  f32x4  __attribute__((ext_vector_type(4)));
typedef float  f32x16 __attribute__((ext_vector_type(16)));
typedef short  short4v __attribute__((ext_vector_type(4)));

__device__ __forceinline__ unsigned short f2bf(float f) {
    unsigned u = __builtin_bit_cast(unsigned, f);
    u += 0x7fffu + ((u >> 16) & 1u);   // RNE
    return (unsigned short)(u >> 16);
}

__device__ __forceinline__ void gload16(const void* g, void* l) {
    __builtin_amdgcn_global_load_lds((const __attribute__((address_space(1))) void*)g,
                                     (__attribute__((address_space(3))) void*)l, 16, 0, 0);
}

// ---------- fp32 -> bf16 convert (vectorized x4) ----------
__global__ void cvt_bf16(const float* __restrict__ in, unsigned short* __restrict__ out, int n) {
    int i = (blockIdx.x * blockDim.x + threadIdx.x) * 4;
    if (i < n) {
        float4 v = *(const float4*)(in + i);
        ushort4 o;
        o.x = f2bf(v.x); o.y = f2bf(v.y); o.z = f2bf(v.z); o.w = f2bf(v.w);
        *(ushort4*)(out + i) = o;
    }
}

// ---------- GEMM C = A * B^T  (A [M,K] row-major bf16, B [N,K] row-major bf16) ----------
#define BM 128
#define BN 128
#define BKK 64

template<int MODE>
__global__ void gemm_bt(const unsigned short* __restrict__ A,
                        const unsigned short* __restrict__ Bm,
                        int M, int N, int K,
                        float* __restrict__ Cf,
                        unsigned short* __restrict__ Qo,
                        unsigned short* __restrict__ Ko,
                        unsigned short* __restrict__ Vo) {
    __shared__ __align__(16) unsigned short Als[BM * BKK];
    __shared__ __align__(16) unsigned short Bls[BN * BKK];

    const int tid  = threadIdx.x;
    const int lane = tid & 63;
    const int wave = tid >> 6;
    const int wm = wave >> 1, wn = wave & 1;
    const int m0 = blockIdx.y * BM, n0 = blockIdx.x * BN;
    const int l16 = lane & 15, lg = lane >> 4;

    f32x4 acc[4][4];
#pragma unroll
    for (int i = 0; i < 4; i++)
#pragma unroll
        for (int j = 0; j < 4; j++) acc[i][j] = f32x4{0.f, 0.f, 0.f, 0.f};

    const int r0 = tid >> 3;   // row 0..31
    const int c8 = tid & 7;    // 16B chunk

    for (int k0 = 0; k0 < K; k0 += BKK) {
        __syncthreads();
#pragma unroll
        for (int i = 0; i < 4; i++) {
            gload16(A  + (size_t)(m0 + r0 + i * 32) * K + k0 + c8 * 8,
                    Als + i * 2048 + wave * 512);
            gload16(Bm + (size_t)(n0 + r0 + i * 32) * K + k0 + c8 * 8,
                    Bls + i * 2048 + wave * 512);
        }
        __syncthreads();
#pragma unroll
        for (int ks = 0; ks < 2; ++ks) {
            const int koff = ks * 32 + lg * 8;
            bf16x8 af[4], bfv[4];
#pragma unroll
            for (int mf = 0; mf < 4; ++mf)
                af[mf] = *(const bf16x8*)(Als + (wm * 64 + mf * 16 + l16) * BKK + koff);
#pragma unroll
            for (int nf = 0; nf < 4; ++nf)
                bfv[nf] = *(const bf16x8*)(Bls + (wn * 64 + nf * 16 + l16) * BKK + koff);
#pragma unroll
            for (int mf = 0; mf < 4; ++mf)
#pragma unroll
                for (int nf = 0; nf < 4; ++nf)
                    acc[mf][nf] = __builtin_amdgcn_mfma_f32_16x16x32_bf16(af[mf], bfv[nf], acc[mf][nf], 0, 0, 0);
        }
    }

#pragma unroll
    for (int mf = 0; mf < 4; ++mf) {
        int gm = m0 + wm * 64 + mf * 16 + (lg << 2);
#pragma unroll
        for (int nf = 0; nf < 4; ++nf) {
            int gn = n0 + wn * 64 + nf * 16 + l16;
            if (MODE == 0) {
                int which = gn >> 10;
                int rem = gn & 1023;
                int h = rem >> 6, d = rem & 63;
                unsigned short* dst = (which == 0) ? Qo : (which == 1) ? Ko : Vo;
                float s = (which == 0) ? 0.180336884f : 1.0f;   // 0.125 * log2(e) for Q
#pragma unroll
                for (int j = 0; j < 4; j++) {
                    int m = gm + j;
                    int b = m >> 11, t = m & 2047;
                    dst[((size_t)((b << 4) + h) * 2048 + t) * 64 + d] = f2bf(acc[mf][nf][j] * s);
                }
            } else {
#pragma unroll
                for (int j = 0; j < 4; j++)
                    Cf[(size_t)(gm + j) * N + gn] = acc[mf][nf][j];
            }
        }
    }
}

// ---------- causal flash attention (32x32 swapped MFMA, in-register softmax) ----------
// grid (32 q-tiles, B*H), 128 threads = 2 waves, each wave owns 32 q-rows (QBLK=64).
// S^T = mfma_32x32x16(K_frag, Q_frag): lane owns q-row = lane&31; 32 key-scores in regs.
// C/D: col=lane&31, row=(reg&3)+8*(reg>>2)+4*(lane>>5). Lane l / l^32 hold complementary
// 4-key halves of each 8-key chunk -> P chunks assemble in LDS via b64 writes, b128 reads.
// Defer-max (T13): skip O/l rescale when wave-uniform max growth <= 2^11.
__global__ __launch_bounds__(128, 2)
void attn_fwd(const unsigned short* __restrict__ Q,
              const unsigned short* __restrict__ Kg,
              const unsigned short* __restrict__ V,
              unsigned short* __restrict__ O) {
    __shared__ __align__(16) unsigned short Kls[64 * 64];
    __shared__ __align__(16) unsigned short Vt[64 * 64];    // [dim][key], swizzled
    __shared__ __align__(16) unsigned short Pls[2][32 * 64];

    const int tid = threadIdx.x, lane = tid & 63, wv = tid >> 6;
    const int l31 = lane & 31, b5 = lane >> 5;
    const int bh = blockIdx.y, qt = blockIdx.x;
    const int q0 = qt * 64;
    const size_t base = (size_t)bh * 2048 * 64;
    const unsigned short* Qp = Q + base;
    const unsigned short* Kp = Kg + base;
    const unsigned short* Vp = V + base;
    const int sr  = tid >> 3;   // staging row 0..15
    const int sc8 = tid & 7;    // staging 16B chunk
    const int b = bh >> 4, h = bh & 15;
    const int qrow = q0 + wv * 32 + l31;
    const int nt = qt + 1;
    const int pswz = ((l31 ^ (l31 >> 3)) & 7) << 3;

    // Q fragments in regs (pre-scaled by 0.125*log2e): Q[d = m*16 + b5*8 + j][q = l31]
    bf16x8 qf[4];
#pragma unroll
    for (int m = 0; m < 4; m++)
        qf[m] = *(const bf16x8*)(Qp + (size_t)qrow * 64 + m * 16 + b5 * 8);

    float mst = -INFINITY, lsum = 0.f;
    f32x16 oacc[2];
#pragma unroll
    for (int r = 0; r < 16; r++) { oacc[0][r] = 0.f; oacc[1][r] = 0.f; }

    // prefetch tile 0
    uint4 kreg[4], vreg[4];
#pragma unroll
    for (int i = 0; i < 4; i++) {
        int r = sr + i * 16;
        kreg[i] = *(const uint4*)(Kp + (size_t)r * 64 + sc8 * 8);
        vreg[i] = *(const uint4*)(Vp + (size_t)r * 64 + sc8 * 8);
    }

    for (int kt = 0; kt < nt; ++kt) {
        __syncthreads();
#pragma unroll
        for (int i = 0; i < 4; i++) {
            int r = sr + i * 16;
            *(uint4*)(Kls + r * 64 + ((sc8 ^ (r & 7)) << 3)) = kreg[i];
            const unsigned short* pv = (const unsigned short*)&vreg[i];
#pragma unroll
            for (int j = 0; j < 8; j++) {
                int d = sc8 * 8 + j;
                Vt[d * 64 + (r ^ ((j ^ sc8) << 3))] = pv[j];   // swz = (d ^ (d>>3)) & 7
            }
        }
        __syncthreads();
        if (kt + 1 < nt) {
#pragma unroll
            for (int i = 0; i < 4; i++) {
                int r = sr + i * 16;
                kreg[i] = *(const uint4*)(Kp + (size_t)((kt + 1) * 64 + r) * 64 + sc8 * 8);
                vreg[i] = *(const uint4*)(Vp + (size_t)((kt + 1) * 64 + r) * 64 + sc8 * 8);
            }
        }

        // S^T = K Q^T : two key-tiles of 32, k-dim = d (4 steps of 16)
        f32x16 s0, s1;
#pragma unroll
        for (int r = 0; r < 16; r++) { s0[r] = 0.f; s1[r] = 0.f; }
#pragma unroll
        for (int m = 0; m < 4; m++) {
            const int koff = m * 16 + b5 * 8;
            int k0i = l31;
            int k1i = 32 + l31;
            bf16x8 kf0 = *(const bf16x8*)(Kls + k0i * 64 + (koff ^ ((k0i & 7) << 3)));
            bf16x8 kf1 = *(const bf16x8*)(Kls + k1i * 64 + (koff ^ ((k1i & 7) << 3)));
            s0 = __builtin_amdgcn_mfma_f32_32x32x16_bf16(kf0, qf[m], s0, 0, 0, 0);
            s1 = __builtin_amdgcn_mfma_f32_32x32x16_bf16(kf1, qf[m], s1, 0, 0, 0);
        }

        // causal mask on diagonal tile
        if (kt == qt) {
#pragma unroll
            for (int r = 0; r < 16; r++) {
                int keyg = kt * 64 + (r & 3) + 8 * (r >> 2) + 4 * b5;
                if (keyg > qrow)      s0[r] = -INFINITY;
                if (keyg + 32 > qrow) s1[r] = -INFINITY;
            }
        }

        // row max (lane-local 32 + one cross-half shfl)
        float xm = fmaxf(s0[0], s1[0]);
#pragma unroll
        for (int r = 1; r < 16; r++) xm = fmaxf(xm, fmaxf(s0[r], s1[r]));
        float x = fmaxf(xm, __shfl_xor(xm, 32));

        // defer-max: only rescale when max grew beyond 2^11
        if (!__all(x - mst <= 11.0f)) {
            float mnew  = fmaxf(mst, x);
            float alpha = __builtin_amdgcn_exp2f(mst - mnew);
            mst = mnew;
            lsum *= alpha;
#pragma unroll
            for (int r = 0; r < 16; r++) { oacc[0][r] *= alpha; oacc[1][r] *= alpha; }
        }

        float ra = 0.f, rb = 0.f;
#pragma unroll
        for (int r = 0; r < 16; r++) {
            s0[r] = __builtin_amdgcn_exp2f(s0[r] - mst);
            s1[r] = __builtin_amdgcn_exp2f(s1[r] - mst);
            ra += s0[r]; rb += s1[r];
        }
        float rs = ra + rb;
        rs += __shfl_xor(rs, 32);
        lsum += rs;

        // P -> LDS: row = q (l31); chunk (c*4+g), half 4*b5; swizzled by pswz
#pragma unroll
        for (int c = 0; c < 2; c++)
#pragma unroll
            for (int g = 0; g < 4; g++) {
                short4v pk;
#pragma unroll
                for (int jj = 0; jj < 4; jj++)
                    pk[jj] = (short)f2bf(c ? s1[g * 4 + jj] : s0[g * 4 + jj]);
                int key0 = c * 32 + g * 8 + 4 * b5;
                *(short4v*)(&Pls[wv][l31 * 64 + (key0 ^ pswz)]) = pk;
            }

        // O^T += V^T P : k-dim = keys (4 steps of 16), two d-tiles of 32
#pragma unroll
        for (int km = 0; km < 4; km++) {
            const int koff = km * 16 + b5 * 8;
            bf16x8 pf = *(const bf16x8*)(&Pls[wv][l31 * 64 + (koff ^ pswz)]);
#pragma unroll
            for (int dt = 0; dt < 2; dt++) {
                int d = dt * 32 + l31;
                bf16x8 vf = *(const bf16x8*)(Vt + d * 64 + (koff ^ (((d ^ (d >> 3)) & 7) << 3)));
                oacc[dt] = __builtin_amdgcn_mfma_f32_32x32x16_bf16(vf, pf, oacc[dt], 0, 0, 0);
            }
        }
    }

    // epilogue: lane's q-row, d = dt*32 + g*8 + 4*b5 + jj
    float inv = 1.f / lsum;
    unsigned short* orow = O + ((size_t)(b * 2048 + qrow)) * 1024 + h * 64;
#pragma unroll
    for (int dt = 0; dt < 2; dt++)
#pragma unroll
        for (int g = 0; g < 4; g++) {
            short4v ov;
#pragma unroll
            for (int jj = 0; jj < 4; jj++)
                ov[jj] = (short)f2bf(oacc[dt][g * 4 + jj] * inv);
            *(short4v*)(orow + dt * 32 + g * 8 + 4 * b5) = ov;
        }
}

// ---------- launch ----------
extern "C" void kernel_launch(void* const* d_in, const int* in_sizes, int n_in,
                              void* d_out, int out_size, void* d_ws, size_t ws_size,
                              hipStream_t stream) {
    const float* x     = (const float*)d_in[0];
    const float* wqkv  = (const float*)d_in[1];
    const float* wproj = (const float*)d_in[2];
    float* out = (float*)d_out;

    const int BT = 4096;          // B*T
    const int DIM = 1024;
    const int NQKV = 3072;

    unsigned short* ws = (unsigned short*)d_ws;
    unsigned short* xb     = ws;
    unsigned short* wqkvb  = xb + (size_t)BT * DIM;
    unsigned short* wprojb = wqkvb + (size_t)NQKV * DIM;
    unsigned short* qb     = wprojb + (size_t)DIM * DIM;
    unsigned short* kb     = qb + (size_t)BT * DIM;
    unsigned short* vb     = kb + (size_t)BT * DIM;
    unsigned short* attb   = xb;

    cvt_bf16<<<(BT * DIM) / 4 / 256, 256, 0, stream>>>(x, xb, BT * DIM);
    cvt_bf16<<<(NQKV * DIM) / 4 / 256, 256, 0, stream>>>(wqkv, wqkvb, NQKV * DIM);
    cvt_bf16<<<(DIM * DIM) / 4 / 256, 256, 0, stream>>>(wproj, wprojb, DIM * DIM);

    gemm_bt<0><<<dim3(NQKV / BN, BT / BM), 256, 0, stream>>>(xb, wqkvb, BT, NQKV, DIM,
                                                             nullptr, qb, kb, vb);
    attn_fwd<<<dim3(32, 32), 128, 0, stream>>>(qb, kb, vb, attb);

    gemm_bt<1><<<dim3(DIM / BN, BT / BM), 256, 0, stream>>>(attb, wprojb, BT, DIM, DIM,
                                                            out, nullptr, nullptr, nullptr);
}

// Round 5
// 122.123 us; speedup vs baseline: 1.3107x; 1.3107x over previous
//
#include <hip/hip_runtime.h>
#include <hip/hip_bf16.h>
#include <stdint.h>

// ---------- types ----------
typedef __bf16 bf16x8 __attribute__((ext_vector_type(8)));
typedef float  f32x4  __attribute__((ext_vector_type(4)));
typedef short  short4v __attribute__((ext_vector_type(4)));

__device__ __forceinline__ unsigned short f2bf(float f) {
    unsigned u = __builtin_bit_cast(unsigned, f);
    u += 0x7fffu + ((u >> 16) & 1u);   // RNE
    return (unsigned short)(u >> 16);
}

__device__ __forceinline__ void gload16(const void* g, void* l) {
    __builtin_amdgcn_global_load_lds((const __attribute__((address_space(1))) void*)g,
                                     (__attribute__((address_space(3))) void*)l, 16, 0, 0);
}

// ---------- fp32 -> bf16 convert (vectorized x4) ----------
__global__ void cvt_bf16(const float* __restrict__ in, unsigned short* __restrict__ out, int n) {
    int i = (blockIdx.x * blockDim.x + threadIdx.x) * 4;
    if (i < n) {
        float4 v = *(const float4*)(in + i);
        ushort4 o;
        o.x = f2bf(v.x); o.y = f2bf(v.y); o.z = f2bf(v.z); o.w = f2bf(v.w);
        *(ushort4*)(out + i) = o;
    }
}

// ---------- GEMM C = A * B^T  (A [M,K] row-major bf16, B [N,K] row-major bf16) ----------
#define BM 128
#define BN 128
#define BKK 64

template<int MODE>
__global__ void gemm_bt(const unsigned short* __restrict__ A,
                        const unsigned short* __restrict__ Bm,
                        int M, int N, int K,
                        float* __restrict__ Cf,
                        unsigned short* __restrict__ Qo,
                        unsigned short* __restrict__ Ko,
                        unsigned short* __restrict__ Vo) {
    __shared__ __align__(16) unsigned short Als[BM * BKK];
    __shared__ __align__(16) unsigned short Bls[BN * BKK];

    const int tid  = threadIdx.x;
    const int lane = tid & 63;
    const int wave = tid >> 6;
    const int wm = wave >> 1, wn = wave & 1;
    const int m0 = blockIdx.y * BM, n0 = blockIdx.x * BN;
    const int l16 = lane & 15, lg = lane >> 4;

    f32x4 acc[4][4];
#pragma unroll
    for (int i = 0; i < 4; i++)
#pragma unroll
        for (int j = 0; j < 4; j++) acc[i][j] = f32x4{0.f, 0.f, 0.f, 0.f};

    const int r0 = tid >> 3;   // row 0..31
    const int c8 = tid & 7;    // 16B chunk

    for (int k0 = 0; k0 < K; k0 += BKK) {
        __syncthreads();
#pragma unroll
        for (int i = 0; i < 4; i++) {
            gload16(A  + (size_t)(m0 + r0 + i * 32) * K + k0 + c8 * 8,
                    Als + i * 2048 + wave * 512);
            gload16(Bm + (size_t)(n0 + r0 + i * 32) * K + k0 + c8 * 8,
                    Bls + i * 2048 + wave * 512);
        }
        __syncthreads();
#pragma unroll
        for (int ks = 0; ks < 2; ++ks) {
            const int koff = ks * 32 + lg * 8;
            bf16x8 af[4], bfv[4];
#pragma unroll
            for (int mf = 0; mf < 4; ++mf)
                af[mf] = *(const bf16x8*)(Als + (wm * 64 + mf * 16 + l16) * BKK + koff);
#pragma unroll
            for (int nf = 0; nf < 4; ++nf)
                bfv[nf] = *(const bf16x8*)(Bls + (wn * 64 + nf * 16 + l16) * BKK + koff);
#pragma unroll
            for (int mf = 0; mf < 4; ++mf)
#pragma unroll
                for (int nf = 0; nf < 4; ++nf)
                    acc[mf][nf] = __builtin_amdgcn_mfma_f32_16x16x32_bf16(af[mf], bfv[nf], acc[mf][nf], 0, 0, 0);
        }
    }

#pragma unroll
    for (int mf = 0; mf < 4; ++mf) {
        int gm = m0 + wm * 64 + mf * 16 + (lg << 2);
#pragma unroll
        for (int nf = 0; nf < 4; ++nf) {
            int gn = n0 + wn * 64 + nf * 16 + l16;
            if (MODE == 0) {
                int which = gn >> 10;
                int rem = gn & 1023;
                int h = rem >> 6, d = rem & 63;
                unsigned short* dst = (which == 0) ? Qo : (which == 1) ? Ko : Vo;
                float s = (which == 0) ? 0.180336884f : 1.0f;   // 0.125 * log2(e) for Q
#pragma unroll
                for (int j = 0; j < 4; j++) {
                    int m = gm + j;
                    int b = m >> 11, t = m & 2047;
                    dst[((size_t)((b << 4) + h) * 2048 + t) * 64 + d] = f2bf(acc[mf][nf][j] * s);
                }
            } else {
#pragma unroll
                for (int j = 0; j < 4; j++)
                    Cf[(size_t)(gm + j) * N + gn] = acc[mf][nf][j];
            }
        }
    }
}

// ---------- causal flash attention (swapped QK^T, in-register softmax) ----------
// grid (16, B*H), 512 threads = 8 waves. Waves 0-3 -> q-tile bx, waves 4-7 -> q-tile 31-bx.
// Both groups SHARE one K/V staging (common KV prefix): per-block compute uniform (34
// tile-computes), 16 waves/CU resident (2x R3). Compute path identical to verified R3.
__global__ __launch_bounds__(512, 4)
void attn_fwd(const unsigned short* __restrict__ Q,
              const unsigned short* __restrict__ Kg,
              const unsigned short* __restrict__ V,
              unsigned short* __restrict__ O) {
    __shared__ __align__(16) unsigned short Kls[64 * 64];
    __shared__ __align__(16) unsigned short Vt[64 * 64];   // [dim][key], swizzled
    __shared__ __align__(16) unsigned short Pls[8][16 * 64];

    const int tid = threadIdx.x, lane = tid & 63, wv = tid >> 6;
    const int l16 = lane & 15, lg = lane >> 4;
    const int grp = wv >> 2, w4 = wv & 3;
    const int bh = blockIdx.y;
    const int bx = blockIdx.x;
    const size_t base = (size_t)bh * 2048 * 64;
    const unsigned short* Qp = Q + base;
    const unsigned short* Kp = Kg + base;
    const unsigned short* Vp = V + base;
    const int sr  = tid >> 3;   // staging row 0..63
    const int sc8 = tid & 7;    // staging 16B chunk
    const int b = bh >> 4, h = bh & 15;

    const int qt = grp ? (31 - bx) : bx;      // this group's q-tile (64 rows)
    const int q0 = qt * 64;
    const int nt = qt + 1;                    // group computes KV tiles 0..qt
    const int ntblk = (31 - bx) + 1;          // block stages this many tiles (max of groups)
    const int qrow = q0 + w4 * 16 + l16;      // this lane's q-row

    // Q fragments (B-operand layout; Q pre-scaled by 0.125*log2e)
    bf16x8 qf[2];
#pragma unroll
    for (int ks = 0; ks < 2; ks++)
        qf[ks] = *(const bf16x8*)(Qp + (size_t)qrow * 64 + ks * 32 + lg * 8);

    float mst = -INFINITY, lsum = 0.f;
    f32x4 oacc[4];
#pragma unroll
    for (int nf = 0; nf < 4; nf++) oacc[nf] = f32x4{0.f, 0.f, 0.f, 0.f};

    // prefetch tile 0 (one 16B chunk of K and V per thread)
    uint4 kreg, vreg;
    kreg = *(const uint4*)(Kp + (size_t)sr * 64 + sc8 * 8);
    vreg = *(const uint4*)(Vp + (size_t)sr * 64 + sc8 * 8);

    for (int kt = 0; kt < ntblk; ++kt) {
        __syncthreads();   // previous tile's compute done; LDS reusable
        {
            int r = sr;
            *(uint4*)(Kls + r * 64 + ((sc8 ^ (r & 7)) << 3)) = kreg;
            const unsigned short* pv = (const unsigned short*)&vreg;
#pragma unroll
            for (int j = 0; j < 8; j++) {
                int d = sc8 * 8 + j;
                Vt[d * 64 + (r ^ ((j ^ sc8) << 3))] = pv[j];
            }
        }
        __syncthreads();
        if (kt + 1 < ntblk) {
            kreg = *(const uint4*)(Kp + (size_t)((kt + 1) * 64 + sr) * 64 + sc8 * 8);
            vreg = *(const uint4*)(Vp + (size_t)((kt + 1) * 64 + sr) * 64 + sc8 * 8);
        }

        if (kt >= nt) continue;   // this group's q-tile doesn't need this KV tile

        // S^T = K Q^T : lane holds q-row = l16, keys = nf*16 + lg*4 + j
        f32x4 sacc[4];
#pragma unroll
        for (int nf = 0; nf < 4; nf++) sacc[nf] = f32x4{0.f, 0.f, 0.f, 0.f};
#pragma unroll
        for (int ks = 0; ks < 2; ks++) {
            const int koff = ks * 32 + lg * 8;
            bf16x8 kf[4];
#pragma unroll
            for (int nf = 0; nf < 4; nf++) {
                int key = nf * 16 + l16;
                kf[nf] = *(const bf16x8*)(Kls + key * 64 + (koff ^ ((key & 7) << 3)));
            }
#pragma unroll
            for (int nf = 0; nf < 4; nf++)
                sacc[nf] = __builtin_amdgcn_mfma_f32_16x16x32_bf16(kf[nf], qf[ks], sacc[nf], 0, 0, 0);
        }

        // causal mask (diagonal tile only): key > qrow
        if (kt == qt) {
#pragma unroll
            for (int nf = 0; nf < 4; nf++) {
                int keyb = kt * 64 + nf * 16 + (lg << 2);
#pragma unroll
                for (int j = 0; j < 4; j++)
                    if (keyb + j > qrow) sacc[nf][j] = -INFINITY;
            }
        }

        // online softmax: in-register row reduce + 2 cross-lane ops
        float xm[4];
#pragma unroll
        for (int nf = 0; nf < 4; nf++)
            xm[nf] = fmaxf(fmaxf(sacc[nf][0], sacc[nf][1]), fmaxf(sacc[nf][2], sacc[nf][3]));
        float x = fmaxf(fmaxf(xm[0], xm[1]), fmaxf(xm[2], xm[3]));
        x = fmaxf(x, __shfl_xor(x, 16));
        x = fmaxf(x, __shfl_xor(x, 32));
        float mnew  = fmaxf(mst, x);
        float alpha = __builtin_amdgcn_exp2f(mst - mnew);
        mst = mnew;
        float ps[4];
#pragma unroll
        for (int nf = 0; nf < 4; nf++) {
#pragma unroll
            for (int j = 0; j < 4; j++)
                sacc[nf][j] = __builtin_amdgcn_exp2f(sacc[nf][j] - mnew);
            ps[nf] = (sacc[nf][0] + sacc[nf][1]) + (sacc[nf][2] + sacc[nf][3]);
        }
        float rs = (ps[0] + ps[1]) + (ps[2] + ps[3]);
        rs += __shfl_xor(rs, 16);
        rs += __shfl_xor(rs, 32);
        lsum = lsum * alpha + rs;
#pragma unroll
        for (int nf = 0; nf < 4; nf++)
#pragma unroll
            for (int j = 0; j < 4; j++) oacc[nf][j] *= alpha;

        // P -> LDS: row = q (l16), packed 4 keys per ds_write_b64, swizzled
#pragma unroll
        for (int nf = 0; nf < 4; nf++) {
            short4v pk;
#pragma unroll
            for (int j = 0; j < 4; j++) pk[j] = (short)f2bf(sacc[nf][j]);
            int keyb = nf * 16 + (lg << 2);
            *(short4v*)(&Pls[wv][l16 * 64 + (keyb ^ ((l16 & 7) << 3))]) = pk;
        }

        // O^T += V^T P : lane holds q = l16, d = nf*16 + lg*4 + j
#pragma unroll
        for (int ks = 0; ks < 2; ks++) {
            const int koff = ks * 32 + lg * 8;   // key offset
            bf16x8 pf = *(const bf16x8*)(&Pls[wv][l16 * 64 + (koff ^ ((l16 & 7) << 3))]);
            bf16x8 vf[4];
#pragma unroll
            for (int nf = 0; nf < 4; nf++) {
                int d = nf * 16 + l16;
                vf[nf] = *(const bf16x8*)(Vt + d * 64 + (koff ^ (((d & 7) ^ ((d >> 3) & 7)) << 3)));
            }
#pragma unroll
            for (int nf = 0; nf < 4; nf++)
                oacc[nf] = __builtin_amdgcn_mfma_f32_16x16x32_bf16(vf[nf], pf, oacc[nf], 0, 0, 0);
        }
    }

    // epilogue: O^T layout -> O[b, t=qrow, h*64 + d], d = nf*16 + lg*4 + j
    {
        float inv = 1.f / lsum;
        unsigned short* orow = O + ((size_t)(b * 2048 + qrow)) * 1024 + h * 64;
#pragma unroll
        for (int nf = 0; nf < 4; nf++) {
            short4v ov;
#pragma unroll
            for (int j = 0; j < 4; j++) ov[j] = (short)f2bf(oacc[nf][j] * inv);
            *(short4v*)(orow + nf * 16 + (lg << 2)) = ov;
        }
    }
}

// ---------- launch ----------
extern "C" void kernel_launch(void* const* d_in, const int* in_sizes, int n_in,
                              void* d_out, int out_size, void* d_ws, size_t ws_size,
                              hipStream_t stream) {
    const float* x     = (const float*)d_in[0];
    const float* wqkv  = (const float*)d_in[1];
    const float* wproj = (const float*)d_in[2];
    float* out = (float*)d_out;

    const int BT = 4096;          // B*T
    const int DIM = 1024;
    const int NQKV = 3072;

    unsigned short* ws = (unsigned short*)d_ws;
    unsigned short* xb     = ws;
    unsigned short* wqkvb  = xb + (size_t)BT * DIM;
    unsigned short* wprojb = wqkvb + (size_t)NQKV * DIM;
    unsigned short* qb     = wprojb + (size_t)DIM * DIM;
    unsigned short* kb     = qb + (size_t)BT * DIM;
    unsigned short* vb     = kb + (size_t)BT * DIM;
    unsigned short* attb   = xb;

    cvt_bf16<<<(BT * DIM) / 4 / 256, 256, 0, stream>>>(x, xb, BT * DIM);
    cvt_bf16<<<(NQKV * DIM) / 4 / 256, 256, 0, stream>>>(wqkv, wqkvb, NQKV * DIM);
    cvt_bf16<<<(DIM * DIM) / 4 / 256, 256, 0, stream>>>(wproj, wprojb, DIM * DIM);

    gemm_bt<0><<<dim3(NQKV / BN, BT / BM), 256, 0, stream>>>(xb, wqkvb, BT, NQKV, DIM,
                                                             nullptr, qb, kb, vb);
    attn_fwd<<<dim3(16, 32), 512, 0, stream>>>(qb, kb, vb, attb);

    gemm_bt<1><<<dim3(DIM / BN, BT / BM), 256, 0, stream>>>(attb, wprojb, BT, DIM, DIM,
                                                            out, nullptr, nullptr, nullptr);
}

// Round 6
// 115.512 us; speedup vs baseline: 1.3857x; 1.0572x over previous
//
#include <hip/hip_runtime.h>
#include <hip/hip_bf16.h>
#include <stdint.h>

// ---------- types ----------
typedef __bf16 bf16x8 __attribute__((ext_vector_type(8)));
typedef __bf16 bf16x4 __attribute__((ext_vector_type(4)));
typedef float  f32x4  __attribute__((ext_vector_type(4)));

__device__ __forceinline__ unsigned short f2bf(float f) {
    unsigned u = __builtin_bit_cast(unsigned, f);
    u += 0x7fffu + ((u >> 16) & 1u);   // RNE
    return (unsigned short)(u >> 16);
}

__device__ __forceinline__ void gload16(const void* g, void* l) {
    __builtin_amdgcn_global_load_lds((const __attribute__((address_space(1))) void*)g,
                                     (__attribute__((address_space(3))) void*)l, 16, 0, 0);
}

// ---------- fused fp32 -> bf16 convert for x, w_qkv, w_proj (one launch) ----------
#define XN  4194304   // 4096*1024
#define WQN 3145728   // 3072*1024
#define WPN 1048576   // 1024*1024
__global__ void cvt_all(const float* __restrict__ x, const float* __restrict__ wq,
                        const float* __restrict__ wp,
                        unsigned short* __restrict__ xb, unsigned short* __restrict__ wqb,
                        unsigned short* __restrict__ wpb) {
    int i = (blockIdx.x * blockDim.x + threadIdx.x) * 4;
    const float* src; unsigned short* dst; int off;
    if (i < XN)            { src = x;  dst = xb;  off = i; }
    else if (i < XN + WQN) { src = wq; dst = wqb; off = i - XN; }
    else                   { src = wp; dst = wpb; off = i - XN - WQN; }
    float4 v = *(const float4*)(src + off);
    ushort4 o;
    o.x = f2bf(v.x); o.y = f2bf(v.y); o.z = f2bf(v.z); o.w = f2bf(v.w);
    *(ushort4*)(dst + off) = o;
}

// ---------- GEMM C = A * B^T  (A [M,K] row-major bf16, B [N,K] row-major bf16) ----------
// 128x128 tile, BK=64, 4 waves 2x2, global_load_lds width-16 staging, XCD-swizzled grid.
#define BM 128
#define BN 128
#define BKK 64

template<int MODE>
__global__ void gemm_bt(const unsigned short* __restrict__ A,
                        const unsigned short* __restrict__ Bm,
                        int M, int N, int K,
                        float* __restrict__ Cf,
                        unsigned short* __restrict__ Qo,
                        unsigned short* __restrict__ Ko,
                        unsigned short* __restrict__ Vo) {
    __shared__ __align__(16) unsigned short Als[BM * BKK];
    __shared__ __align__(16) unsigned short Bls[BN * BKK];

    const int tid  = threadIdx.x;
    const int lane = tid & 63;
    const int wave = tid >> 6;
    const int wm = wave >> 1, wn = wave & 1;
    // T1: XCD-aware swizzle (grid size divisible by 8 for both GEMMs)
    const int nwg = gridDim.x * gridDim.y;
    const int lid = blockIdx.y * gridDim.x + blockIdx.x;
    const int cpx = nwg >> 3;
    const int swz = (lid & 7) * cpx + (lid >> 3);
    const int m0 = (swz / gridDim.x) * BM, n0 = (swz % gridDim.x) * BN;
    const int l16 = lane & 15, lg = lane >> 4;

    f32x4 acc[4][4];
#pragma unroll
    for (int i = 0; i < 4; i++)
#pragma unroll
        for (int j = 0; j < 4; j++) acc[i][j] = f32x4{0.f, 0.f, 0.f, 0.f};

    const int r0 = tid >> 3;   // row 0..31
    const int c8 = tid & 7;    // 16B chunk

    for (int k0 = 0; k0 < K; k0 += BKK) {
        __syncthreads();
#pragma unroll
        for (int i = 0; i < 4; i++) {
            gload16(A  + (size_t)(m0 + r0 + i * 32) * K + k0 + c8 * 8,
                    Als + i * 2048 + wave * 512);
            gload16(Bm + (size_t)(n0 + r0 + i * 32) * K + k0 + c8 * 8,
                    Bls + i * 2048 + wave * 512);
        }
        __syncthreads();
#pragma unroll
        for (int ks = 0; ks < 2; ++ks) {
            const int koff = ks * 32 + lg * 8;
            bf16x8 af[4], bfv[4];
#pragma unroll
            for (int mf = 0; mf < 4; ++mf)
                af[mf] = *(const bf16x8*)(Als + (wm * 64 + mf * 16 + l16) * BKK + koff);
#pragma unroll
            for (int nf = 0; nf < 4; ++nf)
                bfv[nf] = *(const bf16x8*)(Bls + (wn * 64 + nf * 16 + l16) * BKK + koff);
#pragma unroll
            for (int mf = 0; mf < 4; ++mf)
#pragma unroll
                for (int nf = 0; nf < 4; ++nf)
                    acc[mf][nf] = __builtin_amdgcn_mfma_f32_16x16x32_bf16(af[mf], bfv[nf], acc[mf][nf], 0, 0, 0);
        }
    }

#pragma unroll
    for (int mf = 0; mf < 4; ++mf) {
        int gm = m0 + wm * 64 + mf * 16 + (lg << 2);
#pragma unroll
        for (int nf = 0; nf < 4; ++nf) {
            int gn = n0 + wn * 64 + nf * 16 + l16;
            if (MODE == 0) {
                int which = gn >> 10;
                int rem = gn & 1023;
                int h = rem >> 6, d = rem & 63;
                unsigned short* dst = (which == 0) ? Qo : (which == 1) ? Ko : Vo;
                float s = (which == 0) ? 0.180336884f : 1.0f;   // 0.125 * log2(e) for Q
#pragma unroll
                for (int j = 0; j < 4; j++) {
                    int m = gm + j;
                    int b = m >> 11, t = m & 2047;
                    dst[((size_t)((b << 4) + h) * 2048 + t) * 64 + d] = f2bf(acc[mf][nf][j] * s);
                }
            } else {
#pragma unroll
                for (int j = 0; j < 4; j++)
                    Cf[(size_t)(gm + j) * N + gn] = acc[mf][nf][j];
            }
        }
    }
}

// ---------- causal flash attention (swapped QK^T, in-register softmax) ----------
// grid (16, B*H), 512 threads = 8 waves. Waves 0-3 -> q-tile bx, waves 4-7 -> q-tile 31-bx,
// sharing one K/V staging. Native bf16 casts (v_cvt_pk), defer-max rescale (T13, thr=8).
__global__ __launch_bounds__(512, 4)
void attn_fwd(const unsigned short* __restrict__ Q,
              const unsigned short* __restrict__ Kg,
              const unsigned short* __restrict__ V,
              unsigned short* __restrict__ O) {
    __shared__ __align__(16) unsigned short Kls[64 * 64];
    __shared__ __align__(16) unsigned short Vt[64 * 64];   // [dim][key], swizzled
    __shared__ __align__(16) unsigned short Pls[8][16 * 64];

    const int tid = threadIdx.x, lane = tid & 63, wv = tid >> 6;
    const int l16 = lane & 15, lg = lane >> 4;
    const int grp = wv >> 2, w4 = wv & 3;
    const int bh = blockIdx.y;
    const int bx = blockIdx.x;
    const size_t base = (size_t)bh * 2048 * 64;
    const unsigned short* Qp = Q + base;
    const unsigned short* Kp = Kg + base;
    const unsigned short* Vp = V + base;
    const int sr  = tid >> 3;   // staging row 0..63
    const int sc8 = tid & 7;    // staging 16B chunk
    const int b = bh >> 4, h = bh & 15;

    const int qt = grp ? (31 - bx) : bx;      // this group's q-tile (64 rows)
    const int q0 = qt * 64;
    const int nt = qt + 1;                    // group computes KV tiles 0..qt
    const int ntblk = (31 - bx) + 1;          // block stages this many tiles
    const int qrow = q0 + w4 * 16 + l16;      // this lane's q-row

    // Q fragments (B-operand layout; Q pre-scaled by 0.125*log2e)
    bf16x8 qf[2];
#pragma unroll
    for (int ks = 0; ks < 2; ks++)
        qf[ks] = *(const bf16x8*)(Qp + (size_t)qrow * 64 + ks * 32 + lg * 8);

    float mst = -INFINITY, lsum = 0.f;
    f32x4 oacc[4];
#pragma unroll
    for (int nf = 0; nf < 4; nf++) oacc[nf] = f32x4{0.f, 0.f, 0.f, 0.f};

    // prefetch tile 0 (one 16B chunk of K and V per thread)
    uint4 kreg, vreg;
    kreg = *(const uint4*)(Kp + (size_t)sr * 64 + sc8 * 8);
    vreg = *(const uint4*)(Vp + (size_t)sr * 64 + sc8 * 8);

    for (int kt = 0; kt < ntblk; ++kt) {
        __syncthreads();   // previous tile's compute done; LDS reusable
        {
            int r = sr;
            *(uint4*)(Kls + r * 64 + ((sc8 ^ (r & 7)) << 3)) = kreg;
            const unsigned short* pv = (const unsigned short*)&vreg;
#pragma unroll
            for (int j = 0; j < 8; j++) {
                int d = sc8 * 8 + j;
                Vt[d * 64 + (r ^ ((j ^ sc8) << 3))] = pv[j];
            }
        }
        __syncthreads();
        if (kt + 1 < ntblk) {
            kreg = *(const uint4*)(Kp + (size_t)((kt + 1) * 64 + sr) * 64 + sc8 * 8);
            vreg = *(const uint4*)(Vp + (size_t)((kt + 1) * 64 + sr) * 64 + sc8 * 8);
        }

        if (kt >= nt) continue;   // this group's q-tile doesn't need this KV tile

        // S^T = K Q^T : lane holds q-row = l16, keys = nf*16 + lg*4 + j
        f32x4 sacc[4];
#pragma unroll
        for (int nf = 0; nf < 4; nf++) sacc[nf] = f32x4{0.f, 0.f, 0.f, 0.f};
#pragma unroll
        for (int ks = 0; ks < 2; ks++) {
            const int koff = ks * 32 + lg * 8;
            bf16x8 kf[4];
#pragma unroll
            for (int nf = 0; nf < 4; nf++) {
                int key = nf * 16 + l16;
                kf[nf] = *(const bf16x8*)(Kls + key * 64 + (koff ^ ((key & 7) << 3)));
            }
#pragma unroll
            for (int nf = 0; nf < 4; nf++)
                sacc[nf] = __builtin_amdgcn_mfma_f32_16x16x32_bf16(kf[nf], qf[ks], sacc[nf], 0, 0, 0);
        }

        // causal mask (diagonal tile only): key > qrow
        if (kt == qt) {
#pragma unroll
            for (int nf = 0; nf < 4; nf++) {
                int keyb = kt * 64 + nf * 16 + (lg << 2);
#pragma unroll
                for (int j = 0; j < 4; j++)
                    if (keyb + j > qrow) sacc[nf][j] = -INFINITY;
            }
        }

        // online softmax: in-register row reduce + 2 cross-lane ops, defer-max rescale
        float xm[4];
#pragma unroll
        for (int nf = 0; nf < 4; nf++)
            xm[nf] = fmaxf(fmaxf(sacc[nf][0], sacc[nf][1]), fmaxf(sacc[nf][2], sacc[nf][3]));
        float x = fmaxf(fmaxf(xm[0], xm[1]), fmaxf(xm[2], xm[3]));
        x = fmaxf(x, __shfl_xor(x, 16));
        x = fmaxf(x, __shfl_xor(x, 32));
        if (!__all(x - mst <= 8.0f)) {   // T13: rescale only on real max growth
            float mnew  = fmaxf(mst, x);
            float alpha = __builtin_amdgcn_exp2f(mst - mnew);
            mst = mnew;
            lsum *= alpha;
#pragma unroll
            for (int nf = 0; nf < 4; nf++)
#pragma unroll
                for (int j = 0; j < 4; j++) oacc[nf][j] *= alpha;
        }
        float ps[4];
#pragma unroll
        for (int nf = 0; nf < 4; nf++) {
#pragma unroll
            for (int j = 0; j < 4; j++)
                sacc[nf][j] = __builtin_amdgcn_exp2f(sacc[nf][j] - mst);
            ps[nf] = (sacc[nf][0] + sacc[nf][1]) + (sacc[nf][2] + sacc[nf][3]);
        }
        float rs = (ps[0] + ps[1]) + (ps[2] + ps[3]);
        rs += __shfl_xor(rs, 16);
        rs += __shfl_xor(rs, 32);
        lsum += rs;

        // P -> LDS: row = q (l16), native bf16 casts (v_cvt_pk), b64 writes, swizzled
#pragma unroll
        for (int nf = 0; nf < 4; nf++) {
            bf16x4 pk;
#pragma unroll
            for (int j = 0; j < 4; j++) pk[j] = (__bf16)sacc[nf][j];
            int keyb = nf * 16 + (lg << 2);
            *(bf16x4*)(&Pls[wv][l16 * 64 + (keyb ^ ((l16 & 7) << 3))]) = pk;
        }

        // O^T += V^T P : lane holds q = l16, d = nf*16 + lg*4 + j
#pragma unroll
        for (int ks = 0; ks < 2; ks++) {
            const int koff = ks * 32 + lg * 8;   // key offset
            bf16x8 pf = *(const bf16x8*)(&Pls[wv][l16 * 64 + (koff ^ ((l16 & 7) << 3))]);
            bf16x8 vf[4];
#pragma unroll
            for (int nf = 0; nf < 4; nf++) {
                int d = nf * 16 + l16;
                vf[nf] = *(const bf16x8*)(Vt + d * 64 + (koff ^ (((d & 7) ^ ((d >> 3) & 7)) << 3)));
            }
#pragma unroll
            for (int nf = 0; nf < 4; nf++)
                oacc[nf] = __builtin_amdgcn_mfma_f32_16x16x32_bf16(vf[nf], pf, oacc[nf], 0, 0, 0);
        }
    }

    // epilogue: O^T layout -> O[b, t=qrow, h*64 + d], d = nf*16 + lg*4 + j
    {
        float inv = 1.f / lsum;
        unsigned short* orow = O + ((size_t)(b * 2048 + qrow)) * 1024 + h * 64;
#pragma unroll
        for (int nf = 0; nf < 4; nf++) {
            bf16x4 ov;
#pragma unroll
            for (int j = 0; j < 4; j++) ov[j] = (__bf16)(oacc[nf][j] * inv);
            *(bf16x4*)(orow + nf * 16 + (lg << 2)) = ov;
        }
    }
}

// ---------- launch ----------
extern "C" void kernel_launch(void* const* d_in, const int* in_sizes, int n_in,
                              void* d_out, int out_size, void* d_ws, size_t ws_size,
                              hipStream_t stream) {
    const float* x     = (const float*)d_in[0];
    const float* wqkv  = (const float*)d_in[1];
    const float* wproj = (const float*)d_in[2];
    float* out = (float*)d_out;

    const int BT = 4096;          // B*T
    const int DIM = 1024;
    const int NQKV = 3072;

    unsigned short* ws = (unsigned short*)d_ws;
    unsigned short* xb     = ws;
    unsigned short* wqkvb  = xb + (size_t)BT * DIM;
    unsigned short* wprojb = wqkvb + (size_t)NQKV * DIM;
    unsigned short* qb     = wprojb + (size_t)DIM * DIM;
    unsigned short* kb     = qb + (size_t)BT * DIM;
    unsigned short* vb     = kb + (size_t)BT * DIM;
    unsigned short* attb   = xb;

    cvt_all<<<(XN + WQN + WPN) / 4 / 256, 256, 0, stream>>>(x, wqkv, wproj, xb, wqkvb, wprojb);

    gemm_bt<0><<<dim3(NQKV / BN, BT / BM), 256, 0, stream>>>(xb, wqkvb, BT, NQKV, DIM,
                                                             nullptr, qb, kb, vb);
    attn_fwd<<<dim3(16, 32), 512, 0, stream>>>(qb, kb, vb, attb);

    gemm_bt<1><<<dim3(DIM / BN, BT / BM), 256, 0, stream>>>(attb, wprojb, BT, DIM, DIM,
                                                            out, nullptr, nullptr, nullptr);
}

// Round 7
// 113.173 us; speedup vs baseline: 1.4143x; 1.0207x over previous
//
#include <hip/hip_runtime.h>
#include <hip/hip_bf16.h>
#include <stdint.h>

// ---------- types ----------
typedef __bf16 bf16x8 __attribute__((ext_vector_type(8)));
typedef __bf16 bf16x4 __attribute__((ext_vector_type(4)));
typedef float  f32x4  __attribute__((ext_vector_type(4)));

__device__ __forceinline__ unsigned short f2bf(float f) {
    unsigned u = __builtin_bit_cast(unsigned, f);
    u += 0x7fffu + ((u >> 16) & 1u);   // RNE
    return (unsigned short)(u >> 16);
}

__device__ __forceinline__ void gload16(const void* g, void* l) {
    __builtin_amdgcn_global_load_lds((const __attribute__((address_space(1))) void*)g,
                                     (__attribute__((address_space(3))) void*)l, 16, 0, 0);
}

// ---------- fused fp32 -> bf16 convert for x, w_qkv, w_proj (one launch) ----------
#define XN  4194304   // 4096*1024
#define WQN 3145728   // 3072*1024
#define WPN 1048576   // 1024*1024
__global__ void cvt_all(const float* __restrict__ x, const float* __restrict__ wq,
                        const float* __restrict__ wp,
                        unsigned short* __restrict__ xb, unsigned short* __restrict__ wqb,
                        unsigned short* __restrict__ wpb) {
    int i = (blockIdx.x * blockDim.x + threadIdx.x) * 4;
    const float* src; unsigned short* dst; int off;
    if (i < XN)            { src = x;  dst = xb;  off = i; }
    else if (i < XN + WQN) { src = wq; dst = wqb; off = i - XN; }
    else                   { src = wp; dst = wpb; off = i - XN - WQN; }
    float4 v = *(const float4*)(src + off);
    ushort4 o;
    o.x = f2bf(v.x); o.y = f2bf(v.y); o.z = f2bf(v.z); o.w = f2bf(v.w);
    *(ushort4*)(dst + off) = o;
}

// ---------- GEMM C = A * B^T  (A [M,K] row-major bf16, B [N,K] row-major bf16) ----------
// 128x128 tile, BK=64, 4 waves 2x2, global_load_lds width-16 staging, XCD-swizzled grid.
#define BM 128
#define BN 128
#define BKK 64

template<int MODE>
__global__ void gemm_bt(const unsigned short* __restrict__ A,
                        const unsigned short* __restrict__ Bm,
                        int M, int N, int K,
                        float* __restrict__ Cf,
                        unsigned short* __restrict__ Qo,
                        unsigned short* __restrict__ Ko,
                        unsigned short* __restrict__ Vo) {
    __shared__ __align__(16) unsigned short Als[BM * BKK];
    __shared__ __align__(16) unsigned short Bls[BN * BKK];

    const int tid  = threadIdx.x;
    const int lane = tid & 63;
    const int wave = tid >> 6;
    const int wm = wave >> 1, wn = wave & 1;
    // T1: XCD-aware swizzle (grid size divisible by 8 for both GEMMs)
    const int nwg = gridDim.x * gridDim.y;
    const int lid = blockIdx.y * gridDim.x + blockIdx.x;
    const int cpx = nwg >> 3;
    const int swz = (lid & 7) * cpx + (lid >> 3);
    const int m0 = (swz / gridDim.x) * BM, n0 = (swz % gridDim.x) * BN;
    const int l16 = lane & 15, lg = lane >> 4;

    f32x4 acc[4][4];
#pragma unroll
    for (int i = 0; i < 4; i++)
#pragma unroll
        for (int j = 0; j < 4; j++) acc[i][j] = f32x4{0.f, 0.f, 0.f, 0.f};

    const int r0 = tid >> 3;   // row 0..31
    const int c8 = tid & 7;    // 16B chunk

    for (int k0 = 0; k0 < K; k0 += BKK) {
        __syncthreads();
#pragma unroll
        for (int i = 0; i < 4; i++) {
            gload16(A  + (size_t)(m0 + r0 + i * 32) * K + k0 + c8 * 8,
                    Als + i * 2048 + wave * 512);
            gload16(Bm + (size_t)(n0 + r0 + i * 32) * K + k0 + c8 * 8,
                    Bls + i * 2048 + wave * 512);
        }
        __syncthreads();
#pragma unroll
        for (int ks = 0; ks < 2; ++ks) {
            const int koff = ks * 32 + lg * 8;
            bf16x8 af[4], bfv[4];
#pragma unroll
            for (int mf = 0; mf < 4; ++mf)
                af[mf] = *(const bf16x8*)(Als + (wm * 64 + mf * 16 + l16) * BKK + koff);
#pragma unroll
            for (int nf = 0; nf < 4; ++nf)
                bfv[nf] = *(const bf16x8*)(Bls + (wn * 64 + nf * 16 + l16) * BKK + koff);
#pragma unroll
            for (int mf = 0; mf < 4; ++mf)
#pragma unroll
                for (int nf = 0; nf < 4; ++nf)
                    acc[mf][nf] = __builtin_amdgcn_mfma_f32_16x16x32_bf16(af[mf], bfv[nf], acc[mf][nf], 0, 0, 0);
        }
    }

#pragma unroll
    for (int mf = 0; mf < 4; ++mf) {
        int gm = m0 + wm * 64 + mf * 16 + (lg << 2);
#pragma unroll
        for (int nf = 0; nf < 4; ++nf) {
            int gn = n0 + wn * 64 + nf * 16 + l16;
            if (MODE == 0) {
                int which = gn >> 10;
                int rem = gn & 1023;
                int h = rem >> 6, d = rem & 63;
                unsigned short* dst = (which == 0) ? Qo : (which == 1) ? Ko : Vo;
                float s = (which == 0) ? 0.180336884f : 1.0f;   // 0.125 * log2(e) for Q
#pragma unroll
                for (int j = 0; j < 4; j++) {
                    int m = gm + j;
                    int b = m >> 11, t = m & 2047;
                    dst[((size_t)((b << 4) + h) * 2048 + t) * 64 + d] = f2bf(acc[mf][nf][j] * s);
                }
            } else {
#pragma unroll
                for (int j = 0; j < 4; j++)
                    Cf[(size_t)(gm + j) * N + gn] = acc[mf][nf][j];
            }
        }
    }
}

// ---------- causal flash attention (swapped QK^T, in-register softmax) ----------
// 1D grid of 512 blocks SORTED LONGEST-FIRST (LPT): bid -> qt = 15 - (bid>>5), bh = bid&31.
// QBLK=128: 8 waves x 16 q-rows, ALL waves consume the shared KV prefix (no idle groups).
// Wave's rows live in one KV tile: skip kt > qtw, mask only kt == qtw.
__global__ __launch_bounds__(512, 4)
void attn_fwd(const unsigned short* __restrict__ Q,
              const unsigned short* __restrict__ Kg,
              const unsigned short* __restrict__ V,
              unsigned short* __restrict__ O) {
    __shared__ __align__(16) unsigned short Kls[64 * 64];
    __shared__ __align__(16) unsigned short Vt[64 * 64];   // [dim][key], swizzled
    __shared__ __align__(16) unsigned short Pls[8][16 * 64];

    const int tid = threadIdx.x, lane = tid & 63, wv = tid >> 6;
    const int l16 = lane & 15, lg = lane >> 4;
    const int bid = blockIdx.x;
    const int qt = 15 - (bid >> 5);           // q-tile (128 rows), longest first
    const int bh = bid & 31;
    const size_t base = (size_t)bh * 2048 * 64;
    const unsigned short* Qp = Q + base;
    const unsigned short* Kp = Kg + base;
    const unsigned short* Vp = V + base;
    const int sr  = tid >> 3;   // staging row 0..63
    const int sc8 = tid & 7;    // staging 16B chunk
    const int b = bh >> 4, h = bh & 15;

    const int q0 = qt * 128;
    const int ntblk = 2 * qt + 2;             // KV tiles this block stages
    const int qrow = q0 + wv * 16 + l16;      // this lane's q-row
    const int qtw  = (q0 + wv * 16) >> 6;     // wave's diagonal KV-tile index

    // Q fragments (B-operand layout; Q pre-scaled by 0.125*log2e)
    bf16x8 qf[2];
#pragma unroll
    for (int ks = 0; ks < 2; ks++)
        qf[ks] = *(const bf16x8*)(Qp + (size_t)qrow * 64 + ks * 32 + lg * 8);

    float mst = -INFINITY, lsum = 0.f;
    f32x4 oacc[4];
#pragma unroll
    for (int nf = 0; nf < 4; nf++) oacc[nf] = f32x4{0.f, 0.f, 0.f, 0.f};

    // prefetch tile 0 (one 16B chunk of K and V per thread)
    uint4 kreg, vreg;
    kreg = *(const uint4*)(Kp + (size_t)sr * 64 + sc8 * 8);
    vreg = *(const uint4*)(Vp + (size_t)sr * 64 + sc8 * 8);

    for (int kt = 0; kt < ntblk; ++kt) {
        __syncthreads();   // previous tile's compute done; LDS reusable
        {
            int r = sr;
            *(uint4*)(Kls + r * 64 + ((sc8 ^ (r & 7)) << 3)) = kreg;
            const unsigned short* pv = (const unsigned short*)&vreg;
#pragma unroll
            for (int j = 0; j < 8; j++) {
                int d = sc8 * 8 + j;
                Vt[d * 64 + (r ^ ((j ^ sc8) << 3))] = pv[j];
            }
        }
        __syncthreads();
        if (kt + 1 < ntblk) {
            kreg = *(const uint4*)(Kp + (size_t)((kt + 1) * 64 + sr) * 64 + sc8 * 8);
            vreg = *(const uint4*)(Vp + (size_t)((kt + 1) * 64 + sr) * 64 + sc8 * 8);
        }

        if (kt > qtw) continue;   // fully masked for this wave

        // S^T = K Q^T : lane holds q-row = l16, keys = nf*16 + lg*4 + j
        f32x4 sacc[4];
#pragma unroll
        for (int nf = 0; nf < 4; nf++) sacc[nf] = f32x4{0.f, 0.f, 0.f, 0.f};
#pragma unroll
        for (int ks = 0; ks < 2; ks++) {
            const int koff = ks * 32 + lg * 8;
            bf16x8 kf[4];
#pragma unroll
            for (int nf = 0; nf < 4; nf++) {
                int key = nf * 16 + l16;
                kf[nf] = *(const bf16x8*)(Kls + key * 64 + (koff ^ ((key & 7) << 3)));
            }
#pragma unroll
            for (int nf = 0; nf < 4; nf++)
                sacc[nf] = __builtin_amdgcn_mfma_f32_16x16x32_bf16(kf[nf], qf[ks], sacc[nf], 0, 0, 0);
        }

        // causal mask (wave's diagonal tile only): key > qrow
        if (kt == qtw) {
#pragma unroll
            for (int nf = 0; nf < 4; nf++) {
                int keyb = kt * 64 + nf * 16 + (lg << 2);
#pragma unroll
                for (int j = 0; j < 4; j++)
                    if (keyb + j > qrow) sacc[nf][j] = -INFINITY;
            }
        }

        // online softmax: in-register row reduce + 2 cross-lane ops, defer-max rescale
        float xm[4];
#pragma unroll
        for (int nf = 0; nf < 4; nf++)
            xm[nf] = fmaxf(fmaxf(sacc[nf][0], sacc[nf][1]), fmaxf(sacc[nf][2], sacc[nf][3]));
        float x = fmaxf(fmaxf(xm[0], xm[1]), fmaxf(xm[2], xm[3]));
        x = fmaxf(x, __shfl_xor(x, 16));
        x = fmaxf(x, __shfl_xor(x, 32));
        if (!__all(x - mst <= 8.0f)) {   // T13: rescale only on real max growth
            float mnew  = fmaxf(mst, x);
            float alpha = __builtin_amdgcn_exp2f(mst - mnew);
            mst = mnew;
            lsum *= alpha;
#pragma unroll
            for (int nf = 0; nf < 4; nf++)
#pragma unroll
                for (int j = 0; j < 4; j++) oacc[nf][j] *= alpha;
        }
        float ps[4];
#pragma unroll
        for (int nf = 0; nf < 4; nf++) {
#pragma unroll
            for (int j = 0; j < 4; j++)
                sacc[nf][j] = __builtin_amdgcn_exp2f(sacc[nf][j] - mst);
            ps[nf] = (sacc[nf][0] + sacc[nf][1]) + (sacc[nf][2] + sacc[nf][3]);
        }
        float rs = (ps[0] + ps[1]) + (ps[2] + ps[3]);
        rs += __shfl_xor(rs, 16);
        rs += __shfl_xor(rs, 32);
        lsum += rs;

        // P -> LDS: row = q (l16), native bf16 casts (v_cvt_pk), b64 writes, swizzled
#pragma unroll
        for (int nf = 0; nf < 4; nf++) {
            bf16x4 pk;
#pragma unroll
            for (int j = 0; j < 4; j++) pk[j] = (__bf16)sacc[nf][j];
            int keyb = nf * 16 + (lg << 2);
            *(bf16x4*)(&Pls[wv][l16 * 64 + (keyb ^ ((l16 & 7) << 3))]) = pk;
        }

        // O^T += V^T P : lane holds q = l16, d = nf*16 + lg*4 + j
#pragma unroll
        for (int ks = 0; ks < 2; ks++) {
            const int koff = ks * 32 + lg * 8;   // key offset
            bf16x8 pf = *(const bf16x8*)(&Pls[wv][l16 * 64 + (koff ^ ((l16 & 7) << 3))]);
            bf16x8 vf[4];
#pragma unroll
            for (int nf = 0; nf < 4; nf++) {
                int d = nf * 16 + l16;
                vf[nf] = *(const bf16x8*)(Vt + d * 64 + (koff ^ (((d & 7) ^ ((d >> 3) & 7)) << 3)));
            }
#pragma unroll
            for (int nf = 0; nf < 4; nf++)
                oacc[nf] = __builtin_amdgcn_mfma_f32_16x16x32_bf16(vf[nf], pf, oacc[nf], 0, 0, 0);
        }
    }

    // epilogue: O^T layout -> O[b, t=qrow, h*64 + d], d = nf*16 + lg*4 + j
    {
        float inv = 1.f / lsum;
        unsigned short* orow = O + ((size_t)(b * 2048 + qrow)) * 1024 + h * 64;
#pragma unroll
        for (int nf = 0; nf < 4; nf++) {
            bf16x4 ov;
#pragma unroll
            for (int j = 0; j < 4; j++) ov[j] = (__bf16)(oacc[nf][j] * inv);
            *(bf16x4*)(orow + nf * 16 + (lg << 2)) = ov;
        }
    }
}

// ---------- launch ----------
extern "C" void kernel_launch(void* const* d_in, const int* in_sizes, int n_in,
                              void* d_out, int out_size, void* d_ws, size_t ws_size,
                              hipStream_t stream) {
    const float* x     = (const float*)d_in[0];
    const float* wqkv  = (const float*)d_in[1];
    const float* wproj = (const float*)d_in[2];
    float* out = (float*)d_out;

    const int BT = 4096;          // B*T
    const int DIM = 1024;
    const int NQKV = 3072;

    unsigned short* ws = (unsigned short*)d_ws;
    unsigned short* xb     = ws;
    unsigned short* wqkvb  = xb + (size_t)BT * DIM;
    unsigned short* wprojb = wqkvb + (size_t)NQKV * DIM;
    unsigned short* qb     = wprojb + (size_t)DIM * DIM;
    unsigned short* kb     = qb + (size_t)BT * DIM;
    unsigned short* vb     = kb + (size_t)BT * DIM;
    unsigned short* attb   = xb;

    cvt_all<<<(XN + WQN + WPN) / 4 / 256, 256, 0, stream>>>(x, wqkv, wproj, xb, wqkvb, wprojb);

    gemm_bt<0><<<dim3(NQKV / BN, BT / BM), 256, 0, stream>>>(xb, wqkvb, BT, NQKV, DIM,
                                                             nullptr, qb, kb, vb);
    attn_fwd<<<512, 512, 0, stream>>>(qb, kb, vb, attb);

    gemm_bt<1><<<dim3(DIM / BN, BT / BM), 256, 0, stream>>>(attb, wprojb, BT, DIM, DIM,
                                                            out, nullptr, nullptr, nullptr);
}